// Round 4
// baseline (405.073 us; speedup 1.0000x reference)
//
#include <hip/hip_runtime.h>
#include <hip/hip_bf16.h>

typedef __attribute__((ext_vector_type(8))) short bf16x8;
typedef __attribute__((ext_vector_type(4))) float f32x4;
typedef unsigned short u16;
typedef unsigned int u32;

__device__ __forceinline__ u16 f2bf(float f) {
    u32 u = __float_as_uint(f);
    u = (u + 0x7FFFu + ((u >> 16) & 1u)) >> 16;
    return (u16)u;
}
__device__ __forceinline__ u32 pk2(float a, float b) {
    return (u32)f2bf(a) | ((u32)f2bf(b) << 16);
}
union B8 { u32 u[4]; bf16x8 v; };

// ---------- centers: cn = c/||c|| bf16 row-major [b][k][768] ----------
__global__ __launch_bounds__(256) void k_centers(const float* __restrict__ c, u16* __restrict__ cn) {
    int row = (blockIdx.x << 2) + (threadIdx.x >> 6);   // b*256+k
    int lane = threadIdx.x & 63;
    const float* src = c + (size_t)row * 768;
    float v[12]; float ss = 0.f;
#pragma unroll
    for (int j = 0; j < 12; ++j) { v[j] = src[lane + (j << 6)]; ss += v[j] * v[j]; }
#pragma unroll
    for (int m = 1; m < 64; m <<= 1) ss += __shfl_xor(ss, m, 64);
    float inv = 1.0f / sqrtf(ss);
#pragma unroll
    for (int j = 0; j < 12; ++j)
        cn[(size_t)row * 768 + lane + (j << 6)] = f2bf(v[j] * inv);
}

// ---------- prep: xT[b][d][n] = bf16(x) transposed (unnormalized), invn = 1/(||x||+eps) ----------
__global__ __launch_bounds__(256, 8) void k_prep(const float* __restrict__ x, u16* __restrict__ xT,
                                                 float* __restrict__ invn) {
    const int bid = blockIdx.x;                // 1024 blocks, 64 rows each
    const int t = threadIdx.x, w = t >> 6, lane = t & 63;
    const size_t R = (size_t)bid * 64 + lane;  // global token row
    const int b = bid >> 7;
    const int nb = (bid & 127) << 6;           // n-base within batch
    const float* src = x + R * 768 + w * 192;
    u16* dstb = xT + (size_t)b * 768 * 8192;
    float ss = 0.f;
    __shared__ float ps[4][64];

#pragma unroll 2
    for (int dc = 0; dc < 12; ++dc) {
        const float* p = src + (dc << 4);
        float4 f0 = *reinterpret_cast<const float4*>(p);
        float4 f1 = *reinterpret_cast<const float4*>(p + 4);
        float4 f2 = *reinterpret_cast<const float4*>(p + 8);
        float4 f3 = *reinterpret_cast<const float4*>(p + 12);
        ss += f0.x*f0.x + f0.y*f0.y + f0.z*f0.z + f0.w*f0.w
            + f1.x*f1.x + f1.y*f1.y + f1.z*f1.z + f1.w*f1.w
            + f2.x*f2.x + f2.y*f2.y + f2.z*f2.z + f2.w*f2.w
            + f3.x*f3.x + f3.y*f3.y + f3.z*f3.z + f3.w*f3.w;
        u32 r0 = pk2(f0.x, f0.y), r1 = pk2(f0.z, f0.w);
        u32 r2 = pk2(f1.x, f1.y), r3 = pk2(f1.z, f1.w);
        u32 r4 = pk2(f2.x, f2.y), r5 = pk2(f2.z, f2.w);
        u32 r6 = pk2(f3.x, f3.y), r7 = pk2(f3.z, f3.w);
        // 16x16 u16 transpose within each 16-lane group (lane-bit i <-> col-bit i)
        {   bool up = (lane & 8) != 0;   // lane-bit3 <-> reg-bit2
            u32 tv, sv;
            tv = up ? r0 : r4; sv = (u32)__shfl_xor((int)tv, 8, 64); if (up) r0 = sv; else r4 = sv;
            tv = up ? r1 : r5; sv = (u32)__shfl_xor((int)tv, 8, 64); if (up) r1 = sv; else r5 = sv;
            tv = up ? r2 : r6; sv = (u32)__shfl_xor((int)tv, 8, 64); if (up) r2 = sv; else r6 = sv;
            tv = up ? r3 : r7; sv = (u32)__shfl_xor((int)tv, 8, 64); if (up) r3 = sv; else r7 = sv;
        }
        {   bool up = (lane & 4) != 0;   // lane-bit2 <-> reg-bit1
            u32 tv, sv;
            tv = up ? r0 : r2; sv = (u32)__shfl_xor((int)tv, 4, 64); if (up) r0 = sv; else r2 = sv;
            tv = up ? r1 : r3; sv = (u32)__shfl_xor((int)tv, 4, 64); if (up) r1 = sv; else r3 = sv;
            tv = up ? r4 : r6; sv = (u32)__shfl_xor((int)tv, 4, 64); if (up) r4 = sv; else r6 = sv;
            tv = up ? r5 : r7; sv = (u32)__shfl_xor((int)tv, 4, 64); if (up) r5 = sv; else r7 = sv;
        }
        {   bool up = (lane & 2) != 0;   // lane-bit1 <-> reg-bit0
            u32 tv, sv;
            tv = up ? r0 : r1; sv = (u32)__shfl_xor((int)tv, 2, 64); if (up) r0 = sv; else r1 = sv;
            tv = up ? r2 : r3; sv = (u32)__shfl_xor((int)tv, 2, 64); if (up) r2 = sv; else r3 = sv;
            tv = up ? r4 : r5; sv = (u32)__shfl_xor((int)tv, 2, 64); if (up) r4 = sv; else r5 = sv;
            tv = up ? r6 : r7; sv = (u32)__shfl_xor((int)tv, 2, 64); if (up) r6 = sv; else r7 = sv;
        }
        {   // lane-bit0 <-> u16 half
            u32 sv;
            bool up = (lane & 1) != 0;
            sv = (u32)__shfl_xor((int)r0, 1, 64); r0 = up ? ((r0 & 0xFFFF0000u) | (sv >> 16)) : ((r0 & 0xFFFFu) | (sv << 16));
            sv = (u32)__shfl_xor((int)r1, 1, 64); r1 = up ? ((r1 & 0xFFFF0000u) | (sv >> 16)) : ((r1 & 0xFFFFu) | (sv << 16));
            sv = (u32)__shfl_xor((int)r2, 1, 64); r2 = up ? ((r2 & 0xFFFF0000u) | (sv >> 16)) : ((r2 & 0xFFFFu) | (sv << 16));
            sv = (u32)__shfl_xor((int)r3, 1, 64); r3 = up ? ((r3 & 0xFFFF0000u) | (sv >> 16)) : ((r3 & 0xFFFFu) | (sv << 16));
            sv = (u32)__shfl_xor((int)r4, 1, 64); r4 = up ? ((r4 & 0xFFFF0000u) | (sv >> 16)) : ((r4 & 0xFFFFu) | (sv << 16));
            sv = (u32)__shfl_xor((int)r5, 1, 64); r5 = up ? ((r5 & 0xFFFF0000u) | (sv >> 16)) : ((r5 & 0xFFFFu) | (sv << 16));
            sv = (u32)__shfl_xor((int)r6, 1, 64); r6 = up ? ((r6 & 0xFFFF0000u) | (sv >> 16)) : ((r6 & 0xFFFFu) | (sv << 16));
            sv = (u32)__shfl_xor((int)r7, 1, 64); r7 = up ? ((r7 & 0xFFFF0000u) | (sv >> 16)) : ((r7 & 0xFFFFu) | (sv << 16));
        }
        int d = w * 192 + (dc << 4) + (lane & 15);
        u16* dst = dstb + (size_t)d * 8192 + nb + ((lane >> 4) << 4);
        *reinterpret_cast<uint4*>(dst)     = make_uint4(r0, r1, r2, r3);
        *reinterpret_cast<uint4*>(dst + 8) = make_uint4(r4, r5, r6, r7);
    }
    ps[w][lane] = ss;
    __syncthreads();
    if (t < 64) {
        float s = ps[0][t] + ps[1][t] + ps[2][t] + ps[3][t];
        invn[(size_t)bid * 64 + t] = 1.0f / (sqrtf(s) + 1e-8f);
    }
}

// ---------- GEMM1 (cos^T): zero-LDS loop; softmax over k; probT[k][n] + den ----------
__global__ __launch_bounds__(512, 4) void k_gemm1(const float* __restrict__ x, const u16* __restrict__ cn,
                                                  const float* __restrict__ invn,
                                                  u16* __restrict__ probT, float* __restrict__ den) {
    const int b = blockIdx.y;
    const int nb0 = blockIdx.x << 7;           // 128-token tile
    const int t = threadIdx.x, wave = t >> 6, lane = t & 63;
    const int lr = lane & 15, lg = lane >> 4;
    const int wk = wave >> 1, wn = wave & 1;
    const int k0 = wk << 6;
    const int nb = nb0 + (wn << 6);

    __shared__ u16 P[256][72];
    __shared__ float csum[4][128];

    f32x4 acc[4][4];
#pragma unroll
    for (int kf = 0; kf < 4; ++kf)
#pragma unroll
        for (int nf = 0; nf < 4; ++nf) acc[kf][nf] = (f32x4){0.f, 0.f, 0.f, 0.f};

    const float* xb = x + (size_t)b * 8192 * 768;
    const u16* cnb = cn + (size_t)b * 256 * 768;

#pragma unroll 2
    for (int ds = 0; ds < 24; ++ds) {
        const int d0 = ds << 5;
        bf16x8 a[4];
#pragma unroll
        for (int kf = 0; kf < 4; ++kf)
            a[kf] = *reinterpret_cast<const bf16x8*>(cnb + (size_t)(k0 + (kf << 4) + lr) * 768 + d0 + (lg << 3));
#pragma unroll
        for (int nf = 0; nf < 4; ++nf) {
            const float* xp = xb + (size_t)(nb + (nf << 4) + lr) * 768 + d0 + (lg << 3);
            float4 f0 = *reinterpret_cast<const float4*>(xp);
            float4 f1 = *reinterpret_cast<const float4*>(xp + 4);
            B8 bb;
            bb.u[0] = pk2(f0.x, f0.y); bb.u[1] = pk2(f0.z, f0.w);
            bb.u[2] = pk2(f1.x, f1.y); bb.u[3] = pk2(f1.z, f1.w);
#pragma unroll
            for (int kf = 0; kf < 4; ++kf)
                acc[kf][nf] = __builtin_amdgcn_mfma_f32_16x16x32_bf16(a[kf], bb.v, acc[kf][nf], 0, 0, 0);
        }
    }

    // cos = acc * invn[n]; exp (bounded logits); column sums over all 256 k
    float iv[4];
#pragma unroll
    for (int nf = 0; nf < 4; ++nf) iv[nf] = invn[(size_t)b * 8192 + nb + (nf << 4) + lr];
    float cs[4] = {0.f, 0.f, 0.f, 0.f};
#pragma unroll
    for (int kf = 0; kf < 4; ++kf)
#pragma unroll
        for (int nf = 0; nf < 4; ++nf)
#pragma unroll
            for (int r = 0; r < 4; ++r) {
                float e = __expf(acc[kf][nf][r] * iv[nf]);
                acc[kf][nf][r] = e; cs[nf] += e;
            }
#pragma unroll
    for (int nf = 0; nf < 4; ++nf) {
        cs[nf] += __shfl_xor(cs[nf], 16, 64);
        cs[nf] += __shfl_xor(cs[nf], 32, 64);
    }
    if (lg == 0) {
#pragma unroll
        for (int nf = 0; nf < 4; ++nf) csum[wk][(wn << 6) + (nf << 4) + lr] = cs[nf];
    }
    __syncthreads();
    float rs[4];
#pragma unroll
    for (int nf = 0; nf < 4; ++nf) {
        int i = (wn << 6) + (nf << 4) + lr;
        rs[nf] = 1.0f / (csum[0][i] + csum[1][i] + csum[2][i] + csum[3][i]);
    }

    // prob, den row-sums
    float dr[4][4];
#pragma unroll
    for (int kf = 0; kf < 4; ++kf)
#pragma unroll
        for (int r = 0; r < 4; ++r) dr[kf][r] = 0.f;
#pragma unroll
    for (int kf = 0; kf < 4; ++kf)
#pragma unroll
        for (int nf = 0; nf < 4; ++nf)
#pragma unroll
            for (int r = 0; r < 4; ++r) {
                float p = acc[kf][nf][r] * rs[nf];
                acc[kf][nf][r] = p; dr[kf][r] += p;
            }
#pragma unroll
    for (int kf = 0; kf < 4; ++kf)
#pragma unroll
        for (int r = 0; r < 4; ++r) {
            float v = dr[kf][r];
            v += __shfl_xor(v, 1, 64); v += __shfl_xor(v, 2, 64);
            v += __shfl_xor(v, 4, 64); v += __shfl_xor(v, 8, 64);
            if (lr == 0) atomicAdd(&den[(b << 8) + k0 + (kf << 4) + (lg << 2) + r], v);
        }

    // probT via LDS collect, two n-half rounds
    u16* pTb = probT + (size_t)b * 256 * 8192 + nb0;
    for (int rn = 0; rn < 2; ++rn) {
        __syncthreads();
        if (wn == rn) {
#pragma unroll
            for (int kf = 0; kf < 4; ++kf)
#pragma unroll
                for (int r = 0; r < 4; ++r)
#pragma unroll
                    for (int nf = 0; nf < 4; ++nf)
                        P[k0 + (kf << 4) + (lg << 2) + r][(nf << 4) + lr] = f2bf(acc[kf][nf][r]);
        }
        __syncthreads();
        int row = t >> 1, cb = (t & 1) << 5;
#pragma unroll
        for (int j = 0; j < 4; ++j) {
            uint4 v = *reinterpret_cast<const uint4*>(&P[row][cb + (j << 3)]);
            *reinterpret_cast<uint4*>(pTb + (size_t)row * 8192 + (rn << 6) + cb + (j << 3)) = v;
        }
    }
}

// ---------- GEMM2: num_part[s][b][256k][32d-tile], global-direct fragments ----------
__global__ __launch_bounds__(256, 5) void k_gemm2(const u16* __restrict__ probT, const u16* __restrict__ xT,
                                                  float* __restrict__ num_part) {
    const int bid = blockIdx.x;                // 1536
    const int xcd = bid & 7, idx = bid >> 3;
    const int orig = xcd * 192 + idx;
    const int dt = orig % 24, sb = orig / 24;
    const int s = sb >> 3, b = sb & 7;
    const int d0 = dt << 5;
    const int t = threadIdx.x, wave = t >> 6, lane = t & 63;
    const int lr = lane & 15, lg = lane >> 4;
    const int k0 = wave << 6;

    f32x4 acc[4][2];
#pragma unroll
    for (int kf = 0; kf < 4; ++kf)
#pragma unroll
        for (int f = 0; f < 2; ++f) acc[kf][f] = (f32x4){0.f, 0.f, 0.f, 0.f};

    const u16* pA = probT + (size_t)b * 256 * 8192;
    const u16* pX = xT + (size_t)b * 768 * 8192;
    const int nb0 = (s << 10) + (lg << 3);

#pragma unroll 2
    for (int it = 0; it < 32; ++it) {
        const int nb = nb0 + (it << 5);
        bf16x8 a[4], bb[2];
#pragma unroll
        for (int kf = 0; kf < 4; ++kf)
            a[kf] = *reinterpret_cast<const bf16x8*>(pA + (size_t)(k0 + (kf << 4) + lr) * 8192 + nb);
#pragma unroll
        for (int f = 0; f < 2; ++f)
            bb[f] = *reinterpret_cast<const bf16x8*>(pX + (size_t)(d0 + (f << 4) + lr) * 8192 + nb);
#pragma unroll
        for (int kf = 0; kf < 4; ++kf)
#pragma unroll
            for (int f = 0; f < 2; ++f)
                acc[kf][f] = __builtin_amdgcn_mfma_f32_16x16x32_bf16(a[kf], bb[f], acc[kf][f], 0, 0, 0);
    }

    float* np = num_part + (size_t)(s * 8 + b) * 196608;
#pragma unroll
    for (int kf = 0; kf < 4; ++kf) {
        int kr = k0 + (kf << 4) + (lg << 2);
#pragma unroll
        for (int r = 0; r < 4; ++r)
#pragma unroll
            for (int f = 0; f < 2; ++f)
                np[(size_t)(kr + r) * 768 + d0 + (f << 4) + lr] = acc[kf][f][r];
    }
}

// ---------- finalize ----------
__global__ __launch_bounds__(256) void k_final(const float* __restrict__ num_part, const float* __restrict__ den,
                                               float* __restrict__ out) {
    int i = blockIdx.x * 256 + threadIdx.x;
    float sum = 0.f;
#pragma unroll
    for (int ss = 0; ss < 8; ++ss) sum += num_part[(size_t)ss * 1572864 + i];
    out[i] = sum / (den[i / 768] + 1e-8f);
}

extern "C" void kernel_launch(void* const* d_in, const int* in_sizes, int n_in,
                              void* d_out, int out_size, void* d_ws, size_t ws_size,
                              hipStream_t stream) {
    const float* x = (const float*)d_in[0];
    const float* centers = (const float*)d_in[1];
    float* out = (float*)d_out;
    char* ws = (char*)d_ws;
    u16* cn      = (u16*)ws;                         //   3,145,728 B
    u16* probT   = (u16*)(ws + 3145728);             //  33,554,432 B
    float* den   = (float*)(ws + 36700160);          //       8,192 B
    float* invn  = (float*)(ws + 36708352);          //     262,144 B
    u16* xT      = (u16*)(ws + 36970496);            // 100,663,296 B
    float* numpt = (float*)(ws + 137633792);         //  50,331,648 B (end ~188 MB)

    hipMemsetAsync(den, 0, 8192, stream);
    k_centers<<<512, 256, 0, stream>>>(centers, cn);
    k_prep<<<1024, 256, 0, stream>>>(x, xT, invn);
    k_gemm1<<<dim3(64, 8), 512, 0, stream>>>(x, cn, invn, probT, den);
    k_gemm2<<<1536, 256, 0, stream>>>(probT, xT, numpt);
    k_final<<<6144, 256, 0, stream>>>(numpt, den, out);
}

// Round 5
// 220.352 us; speedup vs baseline: 1.8383x; 1.8383x over previous
//
#include <hip/hip_runtime.h>
#include <hip/hip_bf16.h>

typedef __attribute__((ext_vector_type(8))) short bf16x8;
typedef __attribute__((ext_vector_type(4))) float f32x4;
typedef unsigned short u16;
typedef unsigned int u32;

__device__ __forceinline__ u16 f2bf(float f) {
    u32 u = __float_as_uint(f);
    u = (u + 0x7FFFu + ((u >> 16) & 1u)) >> 16;
    return (u16)u;
}
__device__ __forceinline__ u32 pk2(float a, float b) {
    return (u32)f2bf(a) | ((u32)f2bf(b) << 16);
}

#define GLDS16(g, l) __builtin_amdgcn_global_load_lds( \
    (const __attribute__((address_space(1))) u32*)(g), \
    (__attribute__((address_space(3))) u32*)(l), 16, 0, 0)

// ---------- centers: cn = c/||c|| bf16, granule layout [b][kb24][dc4][k256][8] (R3-proven) ----------
__global__ __launch_bounds__(256) void k_centers(const float* __restrict__ c, u16* __restrict__ cn) {
    int bid = blockIdx.x;                      // 512 blocks, 4 rows each
    int w = threadIdx.x >> 6, lane = threadIdx.x & 63;
    int row = (bid << 2) + w;                  // b*256 + k
    int b = row >> 8;
    __shared__ u16 rb[4][800];
    const float* src = c + (size_t)row * 768;
    float v[12]; float ss = 0.f;
#pragma unroll
    for (int j = 0; j < 12; ++j) { v[j] = src[lane + (j << 6)]; ss += v[j] * v[j]; }
#pragma unroll
    for (int m = 1; m < 64; m <<= 1) ss += __shfl_xor(ss, m, 64);
    float inv = 1.0f / sqrtf(ss);
#pragma unroll
    for (int j = 0; j < 12; ++j) rb[w][lane + (j << 6)] = f2bf(v[j] * inv);
    __syncthreads();
    int t = threadIdx.x;
    int k0 = (bid << 2) & 255;
#pragma unroll
    for (int p = 0; p < 2; ++p) {
        int idx = (p << 8) + t;
        if (idx < 384) {
            int g = idx >> 2, kr = idx & 3;
            uint4 val = *reinterpret_cast<const uint4*>(&rb[kr][g << 3]);
            int kb = g >> 2, dc = g & 3;
            size_t o = ((((size_t)(b * 24 + kb) << 2) + dc) << 8) + k0 + kr;
            *reinterpret_cast<uint4*>(cn + (o << 3)) = val;
        }
    }
}

// ---------- GEMM1: cos + softmax over K + probT[b][k][n] + den; dbuf, 1 barrier/iter ----------
__global__ __launch_bounds__(256, 3) void k_gemm1(const float* __restrict__ x, const u16* __restrict__ cn,
                                                  u16* __restrict__ probT, float* __restrict__ den) {
    const int b = blockIdx.y;
    const int n0 = blockIdx.x << 6;            // 64-token tile
    const int t = threadIdx.x;
    const int wave = t >> 6, lane = t & 63;
    const int lg = lane >> 4, lr = lane & 15;

    __shared__ union {
        struct {
            u16 A[2][4][66][8];                // 8448 B, dc-plane stride 1056B (≡8 mod 32 dwords)
            u16 B[2][4][256][8];               // 32768 B, GLDS-linear granules
        } s;
        u16 T[256][72];                        // 36864 B transpose staging
    } u;
    __shared__ float inv_s[64];
    __shared__ float denp[256];

    denp[t] = 0.f;

    f32x4 acc[16];
#pragma unroll
    for (int f = 0; f < 16; ++f) acc[f] = (f32x4){0.f, 0.f, 0.f, 0.f};

    const char* cnb = (const char*)(cn + (size_t)b * 24 * 4 * 256 * 8);
    const int tok = t >> 2;                    // 0..63 (wave w stages toks 16w..16w+15)
    const int dc = t & 3;
    const float* ap = x + ((size_t)b * 8192 + n0 + tok) * 768 + (dc << 3);

    float sq = 0.f;
    float4 f0, f1;

    auto issueA = [&](int kb) {
        const float* p = ap + (kb << 5);
        f0 = *reinterpret_cast<const float4*>(p);
        f1 = *reinterpret_cast<const float4*>(p + 4);
    };
    auto writeA = [&](int buf) {
        sq += f0.x*f0.x + f0.y*f0.y + f0.z*f0.z + f0.w*f0.w
            + f1.x*f1.x + f1.y*f1.y + f1.z*f1.z + f1.w*f1.w;
        *reinterpret_cast<uint4*>(&u.s.A[buf][dc][tok][0]) =
            make_uint4(pk2(f0.x, f0.y), pk2(f0.z, f0.w), pk2(f1.x, f1.y), pk2(f1.z, f1.w));
    };
    auto issueB = [&](int buf, int kb) {
        const char* src = cnb + (size_t)kb * 16384 + (wave << 12) + (lane << 4);
        char* dst = (char*)&u.s.B[buf][0][0][0] + (wave << 12);
        GLDS16(src, dst);
        GLDS16(src + 1024, dst + 1024);
        GLDS16(src + 2048, dst + 2048);
        GLDS16(src + 3072, dst + 3072);
    };

    // prologue
    issueA(0); issueB(0, 0);
    writeA(0);
    __syncthreads();

    for (int kb = 0; kb < 24; ++kb) {
        int cur = kb & 1, nxt = cur ^ 1;
        if (kb < 23) { issueA(kb + 1); issueB(nxt, kb + 1); }
        bf16x8 a = *reinterpret_cast<const bf16x8*>(&u.s.A[cur][lg][(wave << 4) + lr][0]);
#pragma unroll
        for (int f = 0; f < 16; ++f) {
            bf16x8 bb = *reinterpret_cast<const bf16x8*>(&u.s.B[cur][lg][(f << 4) + lr][0]);
            acc[f] = __builtin_amdgcn_mfma_f32_16x16x32_bf16(a, bb, acc[f], 0, 0, 0);
        }
        if (kb < 23) writeA(nxt);
        __syncthreads();
    }

    // inverse norms: reduce sq over dc (lanes t^1, t^2 share tok)
    sq += __shfl_xor(sq, 1, 64);
    sq += __shfl_xor(sq, 2, 64);
    if ((t & 3) == 0) inv_s[tok] = 1.0f / sqrtf(sq);
    __syncthreads();

    float iv[4];
#pragma unroll
    for (int r = 0; r < 4; ++r) iv[r] = inv_s[(wave << 4) + (lg << 2) + r];

    // softmax over K=256 (logits bounded by |cos|<=~1: no max-subtract)
    float s[4] = {0.f, 0.f, 0.f, 0.f};
#pragma unroll
    for (int f = 0; f < 16; ++f)
#pragma unroll
        for (int r = 0; r < 4; ++r) {
            float ee = __expf(acc[f][r] * iv[r]);
            acc[f][r] = ee; s[r] += ee;
        }
#pragma unroll
    for (int m = 1; m < 16; m <<= 1)
#pragma unroll
        for (int r = 0; r < 4; ++r) s[r] += __shfl_xor(s[r], m, 64);
    float rs[4];
#pragma unroll
    for (int r = 0; r < 4; ++r) rs[r] = 1.0f / s[r];

    // prob, column sums (den), transpose into LDS T[k][token]
#pragma unroll
    for (int f = 0; f < 16; ++f) {
        float p0 = acc[f][0] * rs[0], p1 = acc[f][1] * rs[1];
        float p2 = acc[f][2] * rs[2], p3 = acc[f][3] * rs[3];
        float cs = p0 + p1 + p2 + p3;
        cs += __shfl_xor(cs, 16, 64); cs += __shfl_xor(cs, 32, 64);
        if (lg == 0) atomicAdd(&denp[(f << 4) + lr], cs);
        *reinterpret_cast<ushort4*>(&u.T[(f << 4) + lr][(wave << 4) + (lg << 2)]) =
            make_ushort4(f2bf(p0), f2bf(p1), f2bf(p2), f2bf(p3));
    }
    __syncthreads();

    // coalesced writeout of probT tile [256][64]
    u16* pTb = probT + (size_t)b * 256 * 8192 + n0;
#pragma unroll
    for (int i = 0; i < 8; ++i) {
        int idx = (i << 8) + t;
        int row = idx >> 3, ch = idx & 7;
        *reinterpret_cast<uint4*>(pTb + (size_t)row * 8192 + (ch << 3)) =
            *reinterpret_cast<const uint4*>(&u.T[row][ch << 3]);
    }
    atomicAdd(&den[(b << 8) + t], denp[t]);
}

// ---------- GEMM2 (R2-proven): num_part[s][b][k][d] = sum_n prob[n][k] * x[n][d] ----------
__global__ __launch_bounds__(256) void k_gemm2(const float* __restrict__ x, const u16* __restrict__ probT,
                                               float* __restrict__ num_part) {
    const int b = blockIdx.z;
    const int s = blockIdx.y;
    const int d0 = blockIdx.x << 6;
    const int t = threadIdx.x;
    const int wave = t >> 6, lane = t & 63;
    const int lg = lane >> 4, lr = lane & 15;

    f32x4 acc[4][4];
#pragma unroll
    for (int m = 0; m < 4; ++m)
#pragma unroll
        for (int tt = 0; tt < 4; ++tt) acc[m][tt] = (f32x4){0.f, 0.f, 0.f, 0.f};

    const int n0 = s << 10;
    const u16* pA = probT + (size_t)b * 256 * 8192;
    const float* xB = x + (size_t)b * 8192 * 768;

    for (int kb = 0; kb < 32; ++kb) {
        int nbase = n0 + (kb << 5);
        bf16x8 a[4];
#pragma unroll
        for (int m = 0; m < 4; ++m) {
            int k = (wave << 6) + (m << 4) + lr;
            a[m] = *reinterpret_cast<const bf16x8*>(pA + (size_t)k * 8192 + nbase + (lg << 3));
        }
        const float* xr = xB + (size_t)(nbase + (lg << 3)) * 768 + d0 + lr;
        bf16x8 bb[4];
#pragma unroll
        for (int tt = 0; tt < 4; ++tt)
#pragma unroll
            for (int j = 0; j < 8; ++j) {
                float f = xr[(size_t)j * 768 + (tt << 4)];
                bb[tt][j] = (short)f2bf(f);
            }
#pragma unroll
        for (int m = 0; m < 4; ++m)
#pragma unroll
            for (int tt = 0; tt < 4; ++tt)
                acc[m][tt] = __builtin_amdgcn_mfma_f32_16x16x32_bf16(a[m], bb[tt], acc[m][tt], 0, 0, 0);
    }

    float* np = num_part + ((size_t)s * 8 + b) * 256 * 768;
#pragma unroll
    for (int m = 0; m < 4; ++m) {
        int kb_ = (wave << 6) + (m << 4) + (lg << 2);
#pragma unroll
        for (int reg = 0; reg < 4; ++reg)
#pragma unroll
            for (int tt = 0; tt < 4; ++tt)
                np[(size_t)(kb_ + reg) * 768 + d0 + (tt << 4) + lr] = acc[m][tt][reg];
    }
}

// ---------- finalize: out = sum_s num_part / (den + eps) ----------
__global__ __launch_bounds__(256) void k_final(const float* __restrict__ num_part, const float* __restrict__ den,
                                               float* __restrict__ out) {
    int i = blockIdx.x * 256 + threadIdx.x;
    float sum = 0.f;
#pragma unroll
    for (int ss = 0; ss < 8; ++ss) sum += num_part[(size_t)ss * 1572864 + i];
    out[i] = sum / (den[i / 768] + 1e-8f);
}

extern "C" void kernel_launch(void* const* d_in, const int* in_sizes, int n_in,
                              void* d_out, int out_size, void* d_ws, size_t ws_size,
                              hipStream_t stream) {
    const float* x = (const float*)d_in[0];
    const float* centers = (const float*)d_in[1];
    float* out = (float*)d_out;
    char* ws = (char*)d_ws;
    u16* cn       = (u16*)ws;                    //  3,145,728 B
    u16* probT    = (u16*)(ws + 3145728);        // 33,554,432 B
    float* den    = (float*)(ws + 36700160);     //      8,192 B
    float* numpt  = (float*)(ws + 36708352);     // 50,331,648 B  (total ~87 MB)

    hipMemsetAsync(den, 0, 8192, stream);
    k_centers<<<512, 256, 0, stream>>>(centers, cn);
    k_gemm1<<<dim3(128, 8), 256, 0, stream>>>(x, cn, probT, den);
    k_gemm2<<<dim3(12, 8, 8), 256, 0, stream>>>(x, probT, numpt);
    k_final<<<6144, 256, 0, stream>>>(numpt, den, out);
}

// Round 6
// 177.764 us; speedup vs baseline: 2.2787x; 1.2396x over previous
//
#include <hip/hip_runtime.h>
#include <hip/hip_bf16.h>

typedef __attribute__((ext_vector_type(8))) short bf16x8;
typedef __attribute__((ext_vector_type(4))) float f32x4;
typedef unsigned short u16;
typedef unsigned int u32;

__device__ __forceinline__ u16 f2bf(float f) {
    u32 u = __float_as_uint(f);
    u = (u + 0x7FFFu + ((u >> 16) & 1u)) >> 16;
    return (u16)u;
}
__device__ __forceinline__ u32 pk2(float a, float b) {
    return (u32)f2bf(a) | ((u32)f2bf(b) << 16);
}

#define GLDS16(g, l) __builtin_amdgcn_global_load_lds( \
    (const __attribute__((address_space(1))) u32*)(g), \
    (__attribute__((address_space(3))) u32*)(l), 16, 0, 0)

// ---------- centers: cn = c/||c|| bf16, granule layout [b][kb24][dc4][k256][8] ----------
__global__ __launch_bounds__(256) void k_centers(const float* __restrict__ c, u16* __restrict__ cn) {
    int bid = blockIdx.x;                      // 512 blocks, 4 rows each
    int w = threadIdx.x >> 6, lane = threadIdx.x & 63;
    int row = (bid << 2) + w;                  // b*256 + k
    int b = row >> 8;
    __shared__ u16 rb[4][800];
    const float* src = c + (size_t)row * 768;
    float v[12]; float ss = 0.f;
#pragma unroll
    for (int j = 0; j < 12; ++j) { v[j] = src[lane + (j << 6)]; ss += v[j] * v[j]; }
#pragma unroll
    for (int m = 1; m < 64; m <<= 1) ss += __shfl_xor(ss, m, 64);
    float inv = 1.0f / sqrtf(ss);
#pragma unroll
    for (int j = 0; j < 12; ++j) rb[w][lane + (j << 6)] = f2bf(v[j] * inv);
    __syncthreads();
    int t = threadIdx.x;
    int k0 = (bid << 2) & 255;
#pragma unroll
    for (int p = 0; p < 2; ++p) {
        int idx = (p << 8) + t;
        if (idx < 384) {
            int g = idx >> 2, kr = idx & 3;
            uint4 val = *reinterpret_cast<const uint4*>(&rb[kr][g << 3]);
            int kb = g >> 2, dc = g & 3;
            size_t o = ((((size_t)(b * 24 + kb) << 2) + dc) << 8) + k0 + kr;
            *reinterpret_cast<uint4*>(cn + (o << 3)) = val;
        }
    }
}

// ---------- GEMM1: 128tok x 256K tile, 4 waves each 64tok x 128K; 12 ds_read / 32 MFMA ----------
__global__ __launch_bounds__(256, 2) void k_gemm1(const float* __restrict__ x, const u16* __restrict__ cn,
                                                  u16* __restrict__ probT, float* __restrict__ den) {
    const int b = blockIdx.y;
    const int n0 = blockIdx.x << 7;            // 128-token tile
    const int t = threadIdx.x;
    const int wave = t >> 6, lane = t & 63;
    const int lg = lane >> 4, lr = lane & 15;
    const int wm = wave >> 1, wk = wave & 1;
    const int tok0 = wm << 6;                  // wave token base (0/64)
    const int kb0 = wk << 7;                   // wave K base (0/128)

    __shared__ union {
        struct {
            u16 A[2][4][130][8];               // 16640 B, dc-plane stride 2080B (=8 mod 32 dw)
            u16 B[2][4][256][8];               // 32768 B, GLDS-linear granules
        } s;
        u16 T[256][136];                       // 69632 B transpose staging
    } u;
    __shared__ float inv_s[128];
    __shared__ float ksum[2][128];
    __shared__ float denp[256];

    denp[t] = 0.f;

    f32x4 acc[8][4];
#pragma unroll
    for (int kf = 0; kf < 8; ++kf)
#pragma unroll
        for (int tf = 0; tf < 4; ++tf) acc[kf][tf] = (f32x4){0.f, 0.f, 0.f, 0.f};

    const char* cnb = (const char*)(cn + (size_t)b * 24 * 4 * 256 * 8);
    // A staging: thread handles (tokS, dcS) and (tokS, dcS+2) granules (8 d each)
    const int tokS = ((t >> 1) & 63) + ((t >> 7) << 6);
    const int dcS = t & 1;
    const float* ap = x + ((size_t)b * 8192 + n0 + tokS) * 768 + (dcS << 3);

    float sq = 0.f;
    float4 f0, f1, f2, f3;

    auto issueA = [&](int kb) {
        const float* p = ap + (kb << 5);
        f0 = *reinterpret_cast<const float4*>(p);
        f1 = *reinterpret_cast<const float4*>(p + 4);
        f2 = *reinterpret_cast<const float4*>(p + 16);
        f3 = *reinterpret_cast<const float4*>(p + 20);
    };
    auto writeA = [&](int buf) {
        sq += f0.x*f0.x + f0.y*f0.y + f0.z*f0.z + f0.w*f0.w
            + f1.x*f1.x + f1.y*f1.y + f1.z*f1.z + f1.w*f1.w
            + f2.x*f2.x + f2.y*f2.y + f2.z*f2.z + f2.w*f2.w
            + f3.x*f3.x + f3.y*f3.y + f3.z*f3.z + f3.w*f3.w;
        *reinterpret_cast<uint4*>(&u.s.A[buf][dcS][tokS][0]) =
            make_uint4(pk2(f0.x, f0.y), pk2(f0.z, f0.w), pk2(f1.x, f1.y), pk2(f1.z, f1.w));
        *reinterpret_cast<uint4*>(&u.s.A[buf][dcS + 2][tokS][0]) =
            make_uint4(pk2(f2.x, f2.y), pk2(f2.z, f2.w), pk2(f3.x, f3.y), pk2(f3.z, f3.w));
    };
    auto issueB = [&](int buf, int kb) {
        const char* src = cnb + (size_t)kb * 16384 + (wave << 12) + (lane << 4);
        char* dst = (char*)&u.s.B[buf][0][0][0] + (wave << 12);
        GLDS16(src, dst);
        GLDS16(src + 1024, dst + 1024);
        GLDS16(src + 2048, dst + 2048);
        GLDS16(src + 3072, dst + 3072);
    };

    // prologue
    issueA(0); issueB(0, 0);
    writeA(0);
    __syncthreads();

    for (int kb = 0; kb < 24; ++kb) {
        int cur = kb & 1, nxt = cur ^ 1;
        if (kb < 23) { issueA(kb + 1); issueB(nxt, kb + 1); }
        bf16x8 a[4];
#pragma unroll
        for (int tf = 0; tf < 4; ++tf)
            a[tf] = *reinterpret_cast<const bf16x8*>(&u.s.A[cur][lg][tok0 + (tf << 4) + lr][0]);
#pragma unroll
        for (int kf = 0; kf < 8; ++kf) {
            bf16x8 bb = *reinterpret_cast<const bf16x8*>(&u.s.B[cur][lg][kb0 + (kf << 4) + lr][0]);
#pragma unroll
            for (int tf = 0; tf < 4; ++tf)
                acc[kf][tf] = __builtin_amdgcn_mfma_f32_16x16x32_bf16(a[tf], bb, acc[kf][tf], 0, 0, 0);
        }
        if (kb < 23) writeA(nxt);
        __syncthreads();
    }

    // inverse norms (thread pair t^1 holds the complementary dc granules)
    sq += __shfl_xor(sq, 1, 64);
    if ((t & 1) == 0) inv_s[tokS] = 1.0f / sqrtf(sq);
    __syncthreads();

    float iv[4][4];
#pragma unroll
    for (int tf = 0; tf < 4; ++tf)
#pragma unroll
        for (int r = 0; r < 4; ++r)
            iv[tf][r] = inv_s[tok0 + (tf << 4) + (lg << 2) + r];

    // exp (bounded logits, no max-subtract) + per-token partial sums over this wave's 128 K
    float rowsum[4][4];
#pragma unroll
    for (int tf = 0; tf < 4; ++tf)
#pragma unroll
        for (int r = 0; r < 4; ++r) rowsum[tf][r] = 0.f;
#pragma unroll
    for (int kf = 0; kf < 8; ++kf)
#pragma unroll
        for (int tf = 0; tf < 4; ++tf)
#pragma unroll
            for (int r = 0; r < 4; ++r) {
                float e = __expf(acc[kf][tf][r] * iv[tf][r]);
                acc[kf][tf][r] = e; rowsum[tf][r] += e;
            }
#pragma unroll
    for (int tf = 0; tf < 4; ++tf)
#pragma unroll
        for (int r = 0; r < 4; ++r) {
#pragma unroll
            for (int m = 1; m < 16; m <<= 1) rowsum[tf][r] += __shfl_xor(rowsum[tf][r], m, 64);
        }
    if (lr == 0) {
#pragma unroll
        for (int tf = 0; tf < 4; ++tf)
#pragma unroll
            for (int r = 0; r < 4; ++r)
                ksum[wk][tok0 + (tf << 4) + (lg << 2) + r] = rowsum[tf][r];
    }
    __syncthreads();

    float rs[4][4];
#pragma unroll
    for (int tf = 0; tf < 4; ++tf)
#pragma unroll
        for (int r = 0; r < 4; ++r) {
            int idx = tok0 + (tf << 4) + (lg << 2) + r;
            rs[tf][r] = 1.0f / (ksum[0][idx] + ksum[1][idx]);
        }

    // prob, den column sums, transpose into LDS T[K][token]
    float dcol[8];
#pragma unroll
    for (int kf = 0; kf < 8; ++kf) dcol[kf] = 0.f;
#pragma unroll
    for (int kf = 0; kf < 8; ++kf)
#pragma unroll
        for (int tf = 0; tf < 4; ++tf)
#pragma unroll
            for (int r = 0; r < 4; ++r) {
                float p = acc[kf][tf][r] * rs[tf][r];
                acc[kf][tf][r] = p; dcol[kf] += p;
            }
#pragma unroll
    for (int kf = 0; kf < 8; ++kf) {
        dcol[kf] += __shfl_xor(dcol[kf], 16, 64);
        dcol[kf] += __shfl_xor(dcol[kf], 32, 64);
    }
    if (lg == 0) {
#pragma unroll
        for (int kf = 0; kf < 8; ++kf) atomicAdd(&denp[kb0 + (kf << 4) + lr], dcol[kf]);
    }
#pragma unroll
    for (int kf = 0; kf < 8; ++kf)
#pragma unroll
        for (int tf = 0; tf < 4; ++tf)
            *reinterpret_cast<ushort4*>(&u.T[kb0 + (kf << 4) + lr][tok0 + (tf << 4) + (lg << 2)]) =
                make_ushort4(f2bf(acc[kf][tf][0]), f2bf(acc[kf][tf][1]),
                             f2bf(acc[kf][tf][2]), f2bf(acc[kf][tf][3]));
    __syncthreads();

    // coalesced writeout of probT tile [256][128]
    u16* pTb = probT + (size_t)b * 256 * 8192 + n0;
#pragma unroll
    for (int i = 0; i < 16; ++i) {
        int idx = (i << 8) + t;
        int row = idx >> 4, ch = idx & 15;
        *reinterpret_cast<uint4*>(pTb + (size_t)row * 8192 + (ch << 3)) =
            *reinterpret_cast<const uint4*>(&u.T[row][ch << 3]);
    }
    atomicAdd(&den[(b << 8) + t], denp[t]);
}

// ---------- GEMM2 (R2-proven body + XCD grouping): num_part[s][b][k][d] ----------
__global__ __launch_bounds__(256) void k_gemm2(const float* __restrict__ x, const u16* __restrict__ probT,
                                               float* __restrict__ num_part) {
    const int bid = blockIdx.x;                // 768 blocks
    const int xcd = bid & 7, slot = bid >> 3;
    const int orig = xcd * 96 + slot;
    const int dt = orig % 12, sb = orig / 12;  // 12 d-tiles of one (s,b) share an XCD
    const int s = sb >> 3, b = sb & 7;
    const int d0 = dt << 6;
    const int t = threadIdx.x;
    const int wave = t >> 6, lane = t & 63;
    const int lg = lane >> 4, lr = lane & 15;

    f32x4 acc[4][4];
#pragma unroll
    for (int m = 0; m < 4; ++m)
#pragma unroll
        for (int tt = 0; tt < 4; ++tt) acc[m][tt] = (f32x4){0.f, 0.f, 0.f, 0.f};

    const int n0 = s << 10;
    const u16* pA = probT + (size_t)b * 256 * 8192;
    const float* xB = x + (size_t)b * 8192 * 768;

    for (int kb = 0; kb < 32; ++kb) {
        int nbase = n0 + (kb << 5);
        bf16x8 a[4];
#pragma unroll
        for (int m = 0; m < 4; ++m) {
            int k = (wave << 6) + (m << 4) + lr;
            a[m] = *reinterpret_cast<const bf16x8*>(pA + (size_t)k * 8192 + nbase + (lg << 3));
        }
        const float* xr = xB + (size_t)(nbase + (lg << 3)) * 768 + d0 + lr;
        bf16x8 bb[4];
#pragma unroll
        for (int tt = 0; tt < 4; ++tt)
#pragma unroll
            for (int j = 0; j < 8; ++j) {
                float f = xr[(size_t)j * 768 + (tt << 4)];
                bb[tt][j] = (short)f2bf(f);
            }
#pragma unroll
        for (int m = 0; m < 4; ++m)
#pragma unroll
            for (int tt = 0; tt < 4; ++tt)
                acc[m][tt] = __builtin_amdgcn_mfma_f32_16x16x32_bf16(a[m], bb[tt], acc[m][tt], 0, 0, 0);
    }

    float* np = num_part + ((size_t)s * 8 + b) * 256 * 768;
#pragma unroll
    for (int m = 0; m < 4; ++m) {
        int kb_ = (wave << 6) + (m << 4) + (lg << 2);
#pragma unroll
        for (int reg = 0; reg < 4; ++reg)
#pragma unroll
            for (int tt = 0; tt < 4; ++tt)
                np[(size_t)(kb_ + reg) * 768 + d0 + (tt << 4) + lr] = acc[m][tt][reg];
    }
}

// ---------- finalize: out = sum_s num_part / (den + eps) ----------
__global__ __launch_bounds__(256) void k_final(const float* __restrict__ num_part, const float* __restrict__ den,
                                               float* __restrict__ out) {
    int i = blockIdx.x * 256 + threadIdx.x;
    float sum = 0.f;
#pragma unroll
    for (int ss = 0; ss < 8; ++ss) sum += num_part[(size_t)ss * 1572864 + i];
    out[i] = sum / (den[i / 768] + 1e-8f);
}

extern "C" void kernel_launch(void* const* d_in, const int* in_sizes, int n_in,
                              void* d_out, int out_size, void* d_ws, size_t ws_size,
                              hipStream_t stream) {
    const float* x = (const float*)d_in[0];
    const float* centers = (const float*)d_in[1];
    float* out = (float*)d_out;
    char* ws = (char*)d_ws;
    u16* cn       = (u16*)ws;                    //  3,145,728 B
    u16* probT    = (u16*)(ws + 3145728);        // 33,554,432 B
    float* den    = (float*)(ws + 36700160);     //      8,192 B
    float* numpt  = (float*)(ws + 36708352);     // 50,331,648 B  (total ~87 MB)

    hipMemsetAsync(den, 0, 8192, stream);
    k_centers<<<512, 256, 0, stream>>>(centers, cn);
    k_gemm1<<<dim3(64, 8), 256, 0, stream>>>(x, cn, probT, den);
    k_gemm2<<<768, 256, 0, stream>>>(x, probT, numpt);
    k_final<<<6144, 256, 0, stream>>>(numpt, den, out);
}